// Round 17
// baseline (1856.828 us; speedup 1.0000x reference)
//
#include <hip/hip_runtime.h>

// GNODecoder round 17: r16 closed the ledger -- wall 89k cyc/block-tile vs
// 20k VALU: the k-loop's per-iteration GLOBAL B loads (W1+W2=48KB > 32KB L1)
// serialize against L2/L3 latency; occupancy 21->63% never helped (r12).
// Fix: stage ALL weights in LDS once per block (bulk, pipelined staging),
// keep r14's M=128 Cm=8/Cn=8 tile. Per-k: 3-4 LDS reads (B = wave-uniform
// broadcast) vs 64-128 FMA issue cyc -> VALU-majority. LDS 101 KB ->
// 1 block/CU (TLP risk accepted; ILP + compiler's batched ds_reads hide).
// Pins dropped (r16: pure accvgpr-move overhead). proj = plain r7/r9.

#define BLOCK 256

// LDS float offsets
#define OFF_W0   0      // [6][64] = 384
#define OFF_B0   384    // [64]
#define OFF_B1   448    // [64]
#define OFF_B2   512    // [128]
#define OFF_W1   640    // [64][64] = 4096
#define OFF_W2   4736   // [64][128] = 8192
#define OFF_EIN  12928  // [6][132] = 792
#define OFF_HT   13720  // [64][132] = 8448 (h0 then h1)
#define OFF_SACC 22168  // [QB*129]

__device__ __forceinline__ float gelu_f(float x) {
    // jax.nn.gelu default (approximate=True, tanh form)
    float x3 = x * x * x;
    float t  = 0.7978845608028654f * fmaf(0.044715f, x3, x);
    float e  = __expf(2.0f * t);
    float r  = __builtin_amdgcn_rcpf(e + 1.0f);
    return 0.5f * x * (1.0f + (1.0f - 2.0f * r));
}

// ---------- sort machinery (proven) ----------

__global__ void hist_kernel(const int* __restrict__ dst, int* __restrict__ hist, int E) {
    int e = blockIdx.x * blockDim.x + threadIdx.x;
    if (e < E) atomicAdd(&hist[dst[e]], 1);
}

__global__ __launch_bounds__(1024) void scan_kernel(const int* __restrict__ hist,
                                                    int* __restrict__ start, int n) {
    __shared__ int wsum[16];
    __shared__ int woff[16];
    int tid = threadIdx.x;
    int lane = tid & 63, wid = tid >> 6;
    int carry = 0;  // meaningful on tid 0 only
    for (int base = 0; base < n; base += 1024) {
        int i = base + tid;
        int v = (i < n) ? hist[i] : 0;
        int incl = v;
#pragma unroll
        for (int off = 1; off < 64; off <<= 1) {
            int t = __shfl_up(incl, off, 64);
            if (lane >= off) incl += t;
        }
        if (lane == 63) wsum[wid] = incl;
        __syncthreads();
        if (tid == 0) {
            int acc = carry;
#pragma unroll
            for (int w = 0; w < 16; ++w) { woff[w] = acc; acc += wsum[w]; }
            carry = acc;
        }
        __syncthreads();
        if (i < n) start[i] = woff[wid] + incl - v;
        __syncthreads();
    }
    if (threadIdx.x == 0) start[n] = carry;
}

__global__ void scatter_kernel(const int* __restrict__ dst, const int* __restrict__ src,
                               const int* __restrict__ start, int* __restrict__ cursor,
                               int* __restrict__ dsts, int* __restrict__ srcs, int E) {
    int e = blockIdx.x * blockDim.x + threadIdx.x;
    if (e >= E) return;
    int d = dst[e];
    int pos = start[d] + atomicAdd(&cursor[d], 1);
    dsts[pos] = d;
    srcs[pos] = src[e];
}

// ---------- fused: M=128 tiled GEMM, ALL weights in LDS ----------

template <int QB, bool FUSED_PROJ>
__global__ __launch_bounds__(BLOCK, 1) void fused_kernel(
    const float* __restrict__ rndata,   // [NL,128]
    const float* __restrict__ qpos,     // [NQ,3]
    const float* __restrict__ lpos,     // [NL,3]
    const int*   __restrict__ dsts,     // [E] sorted by dst
    const int*   __restrict__ srcs,     // [E]
    const int*   __restrict__ start,    // [NQ+1]
    const float* __restrict__ W0, const float* __restrict__ b0,
    const float* __restrict__ W1, const float* __restrict__ b1,
    const float* __restrict__ W2, const float* __restrict__ b2,
    const float* __restrict__ P0, const float* __restrict__ pb0,
    const float* __restrict__ P1, const float* __restrict__ pb1,
    float* __restrict__ agg,            // [NQ,128] mean (path A)
    float* __restrict__ out,            // [NQ,4]   (FUSED_PROJ)
    int nq)
{
    extern __shared__ float smem[];
    const int tid = threadIdx.x;

    // ---- stage ALL weights into LDS (bulk, pipelined) ----
    {
        const float4* g1 = (const float4*)W1;
        float4* s1 = (float4*)(smem + OFF_W1);
        for (int i = tid; i < 1024; i += BLOCK) s1[i] = g1[i];
        const float4* g2 = (const float4*)W2;
        float4* s2 = (float4*)(smem + OFF_W2);
        for (int i = tid; i < 2048; i += BLOCK) s2[i] = g2[i];
        if (tid < 96)       ((float4*)(smem + OFF_W0))[tid]       = ((const float4*)W0)[tid];
        else if (tid < 112) ((float4*)(smem + OFF_B0))[tid - 96]  = ((const float4*)b0)[tid - 96];
        else if (tid < 128) ((float4*)(smem + OFF_B1))[tid - 112] = ((const float4*)b1)[tid - 112];
        else if (tid < 160) ((float4*)(smem + OFF_B2))[tid - 128] = ((const float4*)b2)[tid - 128];
    }
    for (int i = tid; i < QB * 129; i += BLOCK) smem[OFF_SACC + i] = 0.f;

    float* einT = smem + OFF_EIN;   // [6][132]
    float* hT   = smem + OFF_HT;    // [64][132]
    float* sacc = smem + OFF_SACC;  // [QB][129]

    const int q0   = blockIdx.x * QB;
    const int qend = min(q0 + QB, nq);
    const int e0 = start[q0], e1 = start[qend];
    const int ntiles = (e1 - e0 + 127) >> 7;

    const int w = tid >> 6, lane = tid & 63;
    const int mg = lane & 15, ng = lane >> 4;
    const int mA  = mg * 4;              // rows mA..mA+3 and 64+mA..64+mA+3
    const int nc1 = w * 16 + ng * 4;     // L0/L1 n-base (N=64)
    const int nc2 = w * 32 + ng * 8;     // L2 n-base (N=128)

    for (int t = 0; t < ntiles; ++t) {
        const int ebase = e0 + (t << 7);

        // ---- gather einT (threads 0..127, one edge each) ----
        if (tid < 128) {
            int e = ebase + tid;
            if (e < e1) {
                int d = dsts[e], s = srcs[e];
                einT[0 * 132 + tid] = qpos[d * 3 + 0];
                einT[1 * 132 + tid] = qpos[d * 3 + 1];
                einT[2 * 132 + tid] = qpos[d * 3 + 2];
                einT[3 * 132 + tid] = lpos[s * 3 + 0];
                einT[4 * 132 + tid] = lpos[s * 3 + 1];
                einT[5 * 132 + tid] = lpos[s * 3 + 2];
            } else {
#pragma unroll
                for (int c = 0; c < 6; ++c) einT[c * 132 + tid] = 0.f;
            }
        }
        __syncthreads();  // einT ready (first iter: weight staging too)

        // ---- L0: [128,6] x [6,64] -> hT (h0), Cn=4/Cm=8 ----
        {
            float C[4][8];
            float4 bb = *(const float4*)(smem + OFF_B0 + nc1);
            float bv[4] = {bb.x, bb.y, bb.z, bb.w};
#pragma unroll
            for (int j = 0; j < 4; ++j)
#pragma unroll
                for (int m = 0; m < 8; ++m) C[j][m] = bv[j];
#pragma unroll
            for (int k = 0; k < 6; ++k) {
                float4 a0 = *(const float4*)(einT + k * 132 + mA);
                float4 a1 = *(const float4*)(einT + k * 132 + 64 + mA);
                float av[8] = {a0.x, a0.y, a0.z, a0.w, a1.x, a1.y, a1.z, a1.w};
                float4 B = *(const float4*)(smem + OFF_W0 + k * 64 + nc1);
                float bs[4] = {B.x, B.y, B.z, B.w};
#pragma unroll
                for (int j = 0; j < 4; ++j)
#pragma unroll
                    for (int m = 0; m < 8; ++m)
                        C[j][m] = fmaf(av[m], bs[j], C[j][m]);
            }
#pragma unroll
            for (int j = 0; j < 4; ++j) {
                float4 o0 = make_float4(gelu_f(C[j][0]), gelu_f(C[j][1]),
                                        gelu_f(C[j][2]), gelu_f(C[j][3]));
                float4 o1 = make_float4(gelu_f(C[j][4]), gelu_f(C[j][5]),
                                        gelu_f(C[j][6]), gelu_f(C[j][7]));
                *(float4*)(hT + (nc1 + j) * 132 + mA) = o0;
                *(float4*)(hT + (nc1 + j) * 132 + 64 + mA) = o1;
            }
        }
        __syncthreads();  // h0 ready

        // ---- L1: [128,64] x [64,64], B=W1 from LDS, Cn=4/Cm=8 ----
        float C1[4][8];
        {
            float4 bb = *(const float4*)(smem + OFF_B1 + nc1);
            float bv[4] = {bb.x, bb.y, bb.z, bb.w};
#pragma unroll
            for (int j = 0; j < 4; ++j)
#pragma unroll
                for (int m = 0; m < 8; ++m) C1[j][m] = bv[j];
#pragma unroll 4
            for (int k = 0; k < 64; ++k) {
                float4 a0 = *(const float4*)(hT + k * 132 + mA);
                float4 a1 = *(const float4*)(hT + k * 132 + 64 + mA);
                float av[8] = {a0.x, a0.y, a0.z, a0.w, a1.x, a1.y, a1.z, a1.w};
                float4 B = *(const float4*)(smem + OFF_W1 + k * 64 + nc1);
                float bs[4] = {B.x, B.y, B.z, B.w};
#pragma unroll
                for (int j = 0; j < 4; ++j)
#pragma unroll
                    for (int m = 0; m < 8; ++m)
                        C1[j][m] = fmaf(av[m], bs[j], C1[j][m]);
            }
        }
        __syncthreads();  // all waves done READING h0

        // write h1 = gelu(C1) over hT
#pragma unroll
        for (int j = 0; j < 4; ++j) {
            float4 o0 = make_float4(gelu_f(C1[j][0]), gelu_f(C1[j][1]),
                                    gelu_f(C1[j][2]), gelu_f(C1[j][3]));
            float4 o1 = make_float4(gelu_f(C1[j][4]), gelu_f(C1[j][5]),
                                    gelu_f(C1[j][6]), gelu_f(C1[j][7]));
            *(float4*)(hT + (nc1 + j) * 132 + mA) = o0;
            *(float4*)(hT + (nc1 + j) * 132 + 64 + mA) = o1;
        }
        __syncthreads();  // h1 ready

        // ---- L2: [128,64] x [64,128], B=W2 from LDS, Cn=8/Cm=8 ----
        {
            float C[8][8];
            {
                float4 b20 = *(const float4*)(smem + OFF_B2 + nc2);
                float4 b21 = *(const float4*)(smem + OFF_B2 + nc2 + 4);
                float bv[8] = {b20.x, b20.y, b20.z, b20.w, b21.x, b21.y, b21.z, b21.w};
#pragma unroll
                for (int j = 0; j < 8; ++j)
#pragma unroll
                    for (int m = 0; m < 8; ++m) C[j][m] = bv[j];
            }
#pragma unroll 2
            for (int k = 0; k < 64; ++k) {
                float4 a0 = *(const float4*)(hT + k * 132 + mA);
                float4 a1 = *(const float4*)(hT + k * 132 + 64 + mA);
                float av[8] = {a0.x, a0.y, a0.z, a0.w, a1.x, a1.y, a1.z, a1.w};
                float4 B0 = *(const float4*)(smem + OFF_W2 + k * 128 + nc2);
                float4 B1 = *(const float4*)(smem + OFF_W2 + k * 128 + nc2 + 4);
                float bs[8] = {B0.x, B0.y, B0.z, B0.w, B1.x, B1.y, B1.z, B1.w};
#pragma unroll
                for (int j = 0; j < 8; ++j)
#pragma unroll
                    for (int m = 0; m < 8; ++m)
                        C[j][m] = fmaf(av[m], bs[j], C[j][m]);
            }
            // epilogue: multiply by rndata[src], scatter-add into sacc
#pragma unroll
            for (int m = 0; m < 8; ++m) {
                int row = (m < 4) ? (mA + m) : (64 + mA + m - 4);
                int e = ebase + row;
                if (e < e1) {
                    int d = dsts[e], s = srcs[e];
                    float4 r0 = *(const float4*)(rndata + (size_t)s * 128 + nc2);
                    float4 r1 = *(const float4*)(rndata + (size_t)s * 128 + nc2 + 4);
                    float rs[8] = {r0.x, r0.y, r0.z, r0.w, r1.x, r1.y, r1.z, r1.w};
                    float* ac = &sacc[(d - q0) * 129 + nc2];
#pragma unroll
                    for (int j = 0; j < 8; ++j)
                        atomicAdd(&ac[j], C[j][m] * rs[j]);
                }
            }
        }
        __syncthreads();  // hT/einT safe to overwrite; sacc updates visible
    }
    __syncthreads();  // ntiles==0 path: sacc zero-init visible

    if (!FUSED_PROJ) {
        // write per-query mean to global agg (coalesced across c)
        for (int idx = tid; idx < QB * 128; idx += BLOCK) {
            int ql = idx >> 7, c = idx & 127;
            int q  = q0 + ql;
            if (q < qend) {
                float deg = (float)(start[q + 1] - start[q]);
                agg[(size_t)q * 128 + c] = sacc[ql * 129 + c] / fmaxf(deg, 1.f);
            }
        }
    } else {
        if (tid < QB) {
            int q = q0 + tid;
            if (q < nq) {
                float deg = (float)(start[q + 1] - start[q]);
                float inv = 1.0f / fmaxf(deg, 1.f);
                const float* aq = &sacc[tid * 129];
                float o0 = pb1[0], o1 = pb1[1], o2 = pb1[2], o3 = pb1[3];
#pragma unroll 1
                for (int jj = 0; jj < 256; jj += 8) {
                    float acc[8];
#pragma unroll
                    for (int u = 0; u < 8; ++u) acc[u] = pb0[jj + u];
#pragma unroll
                    for (int i = 0; i < 128; ++i) {
                        float av = aq[i] * inv;
#pragma unroll
                        for (int u = 0; u < 8; ++u)
                            acc[u] = fmaf(av, P0[i * 256 + jj + u], acc[u]);
                    }
#pragma unroll
                    for (int u = 0; u < 8; ++u) {
                        float h = gelu_f(acc[u]);
                        o0 = fmaf(h, P1[(jj + u) * 4 + 0], o0);
                        o1 = fmaf(h, P1[(jj + u) * 4 + 1], o1);
                        o2 = fmaf(h, P1[(jj + u) * 4 + 2], o2);
                        o3 = fmaf(h, P1[(jj + u) * 4 + 3], o3);
                    }
                }
                float4* o4 = (float4*)(out + (size_t)q * 4);
                *o4 = make_float4(o0, o1, o2, o3);
            }
        }
    }
}

// ---------- projection: plain r7/r9 kernel (proven ~270 us) ----------

__global__ __launch_bounds__(256) void proj_kernel(
    const float* __restrict__ agg,      // [NQ,128] mean
    const float* __restrict__ P0, const float* __restrict__ pb0,
    const float* __restrict__ P1, const float* __restrict__ pb1,
    float* __restrict__ out, int nq)
{
    int q = blockIdx.x * blockDim.x + threadIdx.x;
    if (q >= nq) return;

    float a[128];
    const float4* ag4 = (const float4*)(agg + (size_t)q * 128);
#pragma unroll
    for (int i = 0; i < 32; ++i) {
        float4 v = ag4[i];
        a[4 * i + 0] = v.x; a[4 * i + 1] = v.y;
        a[4 * i + 2] = v.z; a[4 * i + 3] = v.w;
    }

    float o0 = pb1[0], o1 = pb1[1], o2 = pb1[2], o3 = pb1[3];
#pragma unroll 1
    for (int jj = 0; jj < 256; jj += 8) {
        float acc[8];
#pragma unroll
        for (int u = 0; u < 8; ++u) acc[u] = pb0[jj + u];
#pragma unroll
        for (int i = 0; i < 128; ++i) {
            float av = a[i];
#pragma unroll
            for (int u = 0; u < 8; ++u)
                acc[u] = fmaf(av, P0[i * 256 + jj + u], acc[u]);
        }
#pragma unroll
        for (int u = 0; u < 8; ++u) {
            float h = gelu_f(acc[u]);
            o0 = fmaf(h, P1[(jj + u) * 4 + 0], o0);
            o1 = fmaf(h, P1[(jj + u) * 4 + 1], o1);
            o2 = fmaf(h, P1[(jj + u) * 4 + 2], o2);
            o3 = fmaf(h, P1[(jj + u) * 4 + 3], o3);
        }
    }
    float4* o4 = (float4*)(out + (size_t)q * 4);
    *o4 = make_float4(o0, o1, o2, o3);
}

extern "C" void kernel_launch(void* const* d_in, const int* in_sizes, int n_in,
                              void* d_out, int out_size, void* d_ws, size_t ws_size,
                              hipStream_t stream)
{
    const float* rndata = (const float*)d_in[0];
    const float* qpos   = (const float*)d_in[1];
    const float* lpos   = (const float*)d_in[2];
    const int*   dst    = (const int*)d_in[3];
    const int*   src    = (const int*)d_in[4];
    const float* W0  = (const float*)d_in[5];
    const float* b0  = (const float*)d_in[6];
    const float* W1  = (const float*)d_in[7];
    const float* b1  = (const float*)d_in[8];
    const float* W2  = (const float*)d_in[9];
    const float* b2  = (const float*)d_in[10];
    const float* P0  = (const float*)d_in[11];
    const float* pb0 = (const float*)d_in[12];
    const float* P1  = (const float*)d_in[13];
    const float* pb1 = (const float*)d_in[14];

    int nq = in_sizes[1] / 3;
    int E  = in_sizes[3];

    // ws layout: [agg nq*128 (path A)] [hist] [cursor] [start] [dsts] [srcs]
    size_t agg_bytes  = (size_t)nq * 128 * sizeof(float);
    size_t sort_bytes = 0;
    {
        size_t o = 0;
        o += ((size_t)nq * sizeof(int) + 15) & ~(size_t)15;
        o += ((size_t)nq * sizeof(int) + 15) & ~(size_t)15;
        o += ((size_t)(nq + 1) * sizeof(int) + 15) & ~(size_t)15;
        o += ((size_t)E * sizeof(int) + 15) & ~(size_t)15;
        o += ((size_t)E * sizeof(int) + 15) & ~(size_t)15;
        sort_bytes = o;
    }
    bool path_a = (agg_bytes + sort_bytes) <= ws_size;

    size_t off = path_a ? agg_bytes : 0;
    auto alloc = [&](size_t bytes) {
        void* p = (char*)d_ws + off;
        off += (bytes + 15) & ~(size_t)15;
        return p;
    };
    float* agg   = (float*)d_ws;  // path A only
    int* hist    = (int*)alloc((size_t)nq * sizeof(int));
    int* cursor  = (int*)alloc((size_t)nq * sizeof(int));
    int* start   = (int*)alloc((size_t)(nq + 1) * sizeof(int));
    int* dsts    = (int*)alloc((size_t)E * sizeof(int));
    int* srcs    = (int*)alloc((size_t)E * sizeof(int));

    size_t histpad = ((size_t)nq * sizeof(int) + 15) & ~(size_t)15;
    hipMemsetAsync(hist, 0, 2 * histpad, stream);

    hist_kernel<<<(E + 255) / 256, 256, 0, stream>>>(dst, hist, E);
    scan_kernel<<<1, 1024, 0, stream>>>(hist, start, nq);
    scatter_kernel<<<(E + 255) / 256, 256, 0, stream>>>(dst, src, start, cursor, dsts, srcs, E);

    constexpr int    QB   = 24;
    constexpr size_t SMEM = (size_t)(22168 + QB * 129) * 4;  // 101,056 B
    int nb = (nq + QB - 1) / QB;

    if (path_a) {
        (void)hipFuncSetAttribute(
            reinterpret_cast<const void*>(&fused_kernel<QB, false>),
            hipFuncAttributeMaxDynamicSharedMemorySize, (int)SMEM);
        fused_kernel<QB, false><<<nb, BLOCK, SMEM, stream>>>(
            rndata, qpos, lpos, dsts, srcs, start,
            W0, b0, W1, b1, W2, b2, P0, pb0, P1, pb1, agg, nullptr, nq);
        proj_kernel<<<(nq + 255) / 256, 256, 0, stream>>>(
            agg, P0, pb0, P1, pb1, (float*)d_out, nq);
    } else {
        (void)hipFuncSetAttribute(
            reinterpret_cast<const void*>(&fused_kernel<QB, true>),
            hipFuncAttributeMaxDynamicSharedMemorySize, (int)SMEM);
        fused_kernel<QB, true><<<nb, BLOCK, SMEM, stream>>>(
            rndata, qpos, lpos, dsts, srcs, start,
            W0, b0, W1, b1, W2, b2, P0, pb0, P1, pb1, nullptr, (float*)d_out, nq);
    }
}

// Round 18
// 1589.063 us; speedup vs baseline: 1.1685x; 1.1685x over previous
//
#include <hip/hip_runtime.h>

// GNODecoder round 18: r13-r17 ledger -- the wall is fission-inflated LDS
// reads (fissioned C[8][8] re-reads A 8x -> ~1.04 ms, matches r14's 1225).
// Anti-fission attacks on the allocator all failed; r17's LDS-weights lost
// occupancy. New shape: size the C-tile TO FIT the 60-VGPR grant so there
// is nothing to fission: M=64, Cm=4, Cn=8 for L2 (C32+A4+B8 ~ 55 live),
// Cn=4 for L0/L1. Per L2 k: 1 LDS A + 2 global B -> 32 FMAs. LDS 34 KB ->
// 4 blocks/CU. B from global (r17: LDS staging costs more than it saves).

#define BLOCK 256

// LDS float offsets (M=64 tile)
#define OFF_W0   0      // [6][64] = 384
#define OFF_B0   384    // [64]
#define OFF_B1   448    // [64]
#define OFF_B2   512    // [128]
#define OFF_EIN  640    // [6][68] = 408
#define OFF_HT   1048   // [64][68] = 4352 (h0 then h1)
#define OFF_SACC 5400   // [QB*129]

__device__ __forceinline__ float gelu_f(float x) {
    // jax.nn.gelu default (approximate=True, tanh form)
    float x3 = x * x * x;
    float t  = 0.7978845608028654f * fmaf(0.044715f, x3, x);
    float e  = __expf(2.0f * t);
    float r  = __builtin_amdgcn_rcpf(e + 1.0f);
    return 0.5f * x * (1.0f + (1.0f - 2.0f * r));
}

// ---------- sort machinery (proven) ----------

__global__ void hist_kernel(const int* __restrict__ dst, int* __restrict__ hist, int E) {
    int e = blockIdx.x * blockDim.x + threadIdx.x;
    if (e < E) atomicAdd(&hist[dst[e]], 1);
}

__global__ __launch_bounds__(1024) void scan_kernel(const int* __restrict__ hist,
                                                    int* __restrict__ start, int n) {
    __shared__ int wsum[16];
    __shared__ int woff[16];
    int tid = threadIdx.x;
    int lane = tid & 63, wid = tid >> 6;
    int carry = 0;  // meaningful on tid 0 only
    for (int base = 0; base < n; base += 1024) {
        int i = base + tid;
        int v = (i < n) ? hist[i] : 0;
        int incl = v;
#pragma unroll
        for (int off = 1; off < 64; off <<= 1) {
            int t = __shfl_up(incl, off, 64);
            if (lane >= off) incl += t;
        }
        if (lane == 63) wsum[wid] = incl;
        __syncthreads();
        if (tid == 0) {
            int acc = carry;
#pragma unroll
            for (int w = 0; w < 16; ++w) { woff[w] = acc; acc += wsum[w]; }
            carry = acc;
        }
        __syncthreads();
        if (i < n) start[i] = woff[wid] + incl - v;
        __syncthreads();
    }
    if (threadIdx.x == 0) start[n] = carry;
}

__global__ void scatter_kernel(const int* __restrict__ dst, const int* __restrict__ src,
                               const int* __restrict__ start, int* __restrict__ cursor,
                               int* __restrict__ dsts, int* __restrict__ srcs, int E) {
    int e = blockIdx.x * blockDim.x + threadIdx.x;
    if (e >= E) return;
    int d = dst[e];
    int pos = start[d] + atomicAdd(&cursor[d], 1);
    dsts[pos] = d;
    srcs[pos] = src[e];
}

// ---------- fused: M=64 tiled GEMM, no-fission C-tiles ----------

template <int QB, bool FUSED_PROJ>
__global__ __launch_bounds__(BLOCK) void fused_kernel(
    const float* __restrict__ rndata,   // [NL,128]
    const float* __restrict__ qpos,     // [NQ,3]
    const float* __restrict__ lpos,     // [NL,3]
    const int*   __restrict__ dsts,     // [E] sorted by dst
    const int*   __restrict__ srcs,     // [E]
    const int*   __restrict__ start,    // [NQ+1]
    const float* __restrict__ W0, const float* __restrict__ b0,
    const float* __restrict__ W1, const float* __restrict__ b1,
    const float* __restrict__ W2, const float* __restrict__ b2,
    const float* __restrict__ P0, const float* __restrict__ pb0,
    const float* __restrict__ P1, const float* __restrict__ pb1,
    float* __restrict__ agg,            // [NQ,128] mean (path A)
    float* __restrict__ out,            // [NQ,4]   (FUSED_PROJ)
    int nq)
{
    extern __shared__ float smem[];
    const int tid = threadIdx.x;

    // ---- stage small weights (W0 + biases); W1/W2 from global/L1 ----
    if (tid < 96)       ((float4*)(smem + OFF_W0))[tid]       = ((const float4*)W0)[tid];
    else if (tid < 112) ((float4*)(smem + OFF_B0))[tid - 96]  = ((const float4*)b0)[tid - 96];
    else if (tid < 128) ((float4*)(smem + OFF_B1))[tid - 112] = ((const float4*)b1)[tid - 112];
    else if (tid < 160) ((float4*)(smem + OFF_B2))[tid - 128] = ((const float4*)b2)[tid - 128];
    for (int i = tid; i < QB * 129; i += BLOCK) smem[OFF_SACC + i] = 0.f;

    float* einT = smem + OFF_EIN;   // [6][68]
    float* hT   = smem + OFF_HT;    // [64][68]
    float* sacc = smem + OFF_SACC;  // [QB][129]

    const int q0   = blockIdx.x * QB;
    const int qend = min(q0 + QB, nq);
    const int e0 = start[q0], e1 = start[qend];
    const int ntiles = (e1 - e0 + 63) >> 6;

    const int w = tid >> 6, lane = tid & 63;
    const int mg = lane & 15, ng = lane >> 4;
    const int mA  = mg * 4;              // 4 m-rows (edges) per lane
    const int nc1 = w * 16 + ng * 4;     // L0/L1 n-base (N=64, Cn=4)
    const int nc2 = w * 32 + ng * 8;     // L2 n-base (N=128, Cn=8)

    for (int t = 0; t < ntiles; ++t) {
        const int ebase = e0 + (t << 6);

        // ---- gather einT (threads 0..63, one edge each) ----
        if (tid < 64) {
            int e = ebase + tid;
            if (e < e1) {
                int d = dsts[e], s = srcs[e];
                einT[0 * 68 + tid] = qpos[d * 3 + 0];
                einT[1 * 68 + tid] = qpos[d * 3 + 1];
                einT[2 * 68 + tid] = qpos[d * 3 + 2];
                einT[3 * 68 + tid] = lpos[s * 3 + 0];
                einT[4 * 68 + tid] = lpos[s * 3 + 1];
                einT[5 * 68 + tid] = lpos[s * 3 + 2];
            } else {
#pragma unroll
                for (int c = 0; c < 6; ++c) einT[c * 68 + tid] = 0.f;
            }
        }
        __syncthreads();  // einT ready (first iter: staging too)

        // ---- L0: [64,6] x [6,64] -> hT (h0), B from LDS, Cn=4/Cm=4 ----
        {
            float C[4][4];
            float4 bb = *(const float4*)(smem + OFF_B0 + nc1);
            float bv[4] = {bb.x, bb.y, bb.z, bb.w};
#pragma unroll
            for (int j = 0; j < 4; ++j)
#pragma unroll
                for (int m = 0; m < 4; ++m) C[j][m] = bv[j];
#pragma unroll
            for (int k = 0; k < 6; ++k) {
                float4 a = *(const float4*)(einT + k * 68 + mA);
                float av[4] = {a.x, a.y, a.z, a.w};
                float4 B = *(const float4*)(smem + OFF_W0 + k * 64 + nc1);
                float bs[4] = {B.x, B.y, B.z, B.w};
#pragma unroll
                for (int j = 0; j < 4; ++j)
#pragma unroll
                    for (int m = 0; m < 4; ++m)
                        C[j][m] = fmaf(av[m], bs[j], C[j][m]);
            }
#pragma unroll
            for (int j = 0; j < 4; ++j) {
                float4 o = make_float4(gelu_f(C[j][0]), gelu_f(C[j][1]),
                                       gelu_f(C[j][2]), gelu_f(C[j][3]));
                *(float4*)(hT + (nc1 + j) * 68 + mA) = o;
            }
        }
        __syncthreads();  // h0 ready

        // ---- L1: [64,64] x [64,64], B=W1 (global), Cn=4/Cm=4 ----
        float C1[4][4];
        {
            float4 bb = *(const float4*)(smem + OFF_B1 + nc1);
            float bv[4] = {bb.x, bb.y, bb.z, bb.w};
#pragma unroll
            for (int j = 0; j < 4; ++j)
#pragma unroll
                for (int m = 0; m < 4; ++m) C1[j][m] = bv[j];
#pragma unroll 4
            for (int k = 0; k < 64; ++k) {
                float4 a = *(const float4*)(hT + k * 68 + mA);
                float av[4] = {a.x, a.y, a.z, a.w};
                float4 B = *(const float4*)(W1 + k * 64 + nc1);
                float bs[4] = {B.x, B.y, B.z, B.w};
#pragma unroll
                for (int j = 0; j < 4; ++j)
#pragma unroll
                    for (int m = 0; m < 4; ++m)
                        C1[j][m] = fmaf(av[m], bs[j], C1[j][m]);
            }
        }
        __syncthreads();  // all waves done READING h0

        // write h1 = gelu(C1) over hT
#pragma unroll
        for (int j = 0; j < 4; ++j) {
            float4 o = make_float4(gelu_f(C1[j][0]), gelu_f(C1[j][1]),
                                   gelu_f(C1[j][2]), gelu_f(C1[j][3]));
            *(float4*)(hT + (nc1 + j) * 68 + mA) = o;
        }
        __syncthreads();  // h1 ready

        // ---- L2: [64,64] x [64,128], B=W2 (global), Cn=8/Cm=4 ----
        {
            float C[8][4];
            {
                float4 b20 = *(const float4*)(smem + OFF_B2 + nc2);
                float4 b21 = *(const float4*)(smem + OFF_B2 + nc2 + 4);
                float bv[8] = {b20.x, b20.y, b20.z, b20.w, b21.x, b21.y, b21.z, b21.w};
#pragma unroll
                for (int j = 0; j < 8; ++j)
#pragma unroll
                    for (int m = 0; m < 4; ++m) C[j][m] = bv[j];
            }
#pragma unroll 4
            for (int k = 0; k < 64; ++k) {
                float4 a = *(const float4*)(hT + k * 68 + mA);
                float av[4] = {a.x, a.y, a.z, a.w};
                float4 B0 = *(const float4*)(W2 + k * 128 + nc2);
                float4 B1 = *(const float4*)(W2 + k * 128 + nc2 + 4);
                float bs[8] = {B0.x, B0.y, B0.z, B0.w, B1.x, B1.y, B1.z, B1.w};
#pragma unroll
                for (int j = 0; j < 8; ++j)
#pragma unroll
                    for (int m = 0; m < 4; ++m)
                        C[j][m] = fmaf(av[m], bs[j], C[j][m]);
            }
            // epilogue: multiply by rndata[src], scatter-add into sacc
#pragma unroll
            for (int m = 0; m < 4; ++m) {
                int e = ebase + mA + m;
                if (e < e1) {
                    int d = dsts[e], s = srcs[e];
                    float4 r0 = *(const float4*)(rndata + (size_t)s * 128 + nc2);
                    float4 r1 = *(const float4*)(rndata + (size_t)s * 128 + nc2 + 4);
                    float rs[8] = {r0.x, r0.y, r0.z, r0.w, r1.x, r1.y, r1.z, r1.w};
                    float* ac = &sacc[(d - q0) * 129 + nc2];
#pragma unroll
                    for (int j = 0; j < 8; ++j)
                        atomicAdd(&ac[j], C[j][m] * rs[j]);
                }
            }
        }
        __syncthreads();  // hT/einT safe to overwrite; sacc updates visible
    }
    __syncthreads();  // ntiles==0 path: sacc zero-init visible

    if (!FUSED_PROJ) {
        // write per-query mean to global agg (coalesced across c)
        for (int idx = tid; idx < QB * 128; idx += BLOCK) {
            int ql = idx >> 7, c = idx & 127;
            int q  = q0 + ql;
            if (q < qend) {
                float deg = (float)(start[q + 1] - start[q]);
                agg[(size_t)q * 128 + c] = sacc[ql * 129 + c] / fmaxf(deg, 1.f);
            }
        }
    } else {
        if (tid < QB) {
            int q = q0 + tid;
            if (q < nq) {
                float deg = (float)(start[q + 1] - start[q]);
                float inv = 1.0f / fmaxf(deg, 1.f);
                const float* aq = &sacc[tid * 129];
                float o0 = pb1[0], o1 = pb1[1], o2 = pb1[2], o3 = pb1[3];
#pragma unroll 1
                for (int jj = 0; jj < 256; jj += 8) {
                    float acc[8];
#pragma unroll
                    for (int u = 0; u < 8; ++u) acc[u] = pb0[jj + u];
#pragma unroll
                    for (int i = 0; i < 128; ++i) {
                        float av = aq[i] * inv;
#pragma unroll
                        for (int u = 0; u < 8; ++u)
                            acc[u] = fmaf(av, P0[i * 256 + jj + u], acc[u]);
                    }
#pragma unroll
                    for (int u = 0; u < 8; ++u) {
                        float h = gelu_f(acc[u]);
                        o0 = fmaf(h, P1[(jj + u) * 4 + 0], o0);
                        o1 = fmaf(h, P1[(jj + u) * 4 + 1], o1);
                        o2 = fmaf(h, P1[(jj + u) * 4 + 2], o2);
                        o3 = fmaf(h, P1[(jj + u) * 4 + 3], o3);
                    }
                }
                float4* o4 = (float4*)(out + (size_t)q * 4);
                *o4 = make_float4(o0, o1, o2, o3);
            }
        }
    }
}

// ---------- projection: plain r7/r9 kernel (proven ~270 us) ----------

__global__ __launch_bounds__(256) void proj_kernel(
    const float* __restrict__ agg,      // [NQ,128] mean
    const float* __restrict__ P0, const float* __restrict__ pb0,
    const float* __restrict__ P1, const float* __restrict__ pb1,
    float* __restrict__ out, int nq)
{
    int q = blockIdx.x * blockDim.x + threadIdx.x;
    if (q >= nq) return;

    float a[128];
    const float4* ag4 = (const float4*)(agg + (size_t)q * 128);
#pragma unroll
    for (int i = 0; i < 32; ++i) {
        float4 v = ag4[i];
        a[4 * i + 0] = v.x; a[4 * i + 1] = v.y;
        a[4 * i + 2] = v.z; a[4 * i + 3] = v.w;
    }

    float o0 = pb1[0], o1 = pb1[1], o2 = pb1[2], o3 = pb1[3];
#pragma unroll 1
    for (int jj = 0; jj < 256; jj += 8) {
        float acc[8];
#pragma unroll
        for (int u = 0; u < 8; ++u) acc[u] = pb0[jj + u];
#pragma unroll
        for (int i = 0; i < 128; ++i) {
            float av = a[i];
#pragma unroll
            for (int u = 0; u < 8; ++u)
                acc[u] = fmaf(av, P0[i * 256 + jj + u], acc[u]);
        }
#pragma unroll
        for (int u = 0; u < 8; ++u) {
            float h = gelu_f(acc[u]);
            o0 = fmaf(h, P1[(jj + u) * 4 + 0], o0);
            o1 = fmaf(h, P1[(jj + u) * 4 + 1], o1);
            o2 = fmaf(h, P1[(jj + u) * 4 + 2], o2);
            o3 = fmaf(h, P1[(jj + u) * 4 + 3], o3);
        }
    }
    float4* o4 = (float4*)(out + (size_t)q * 4);
    *o4 = make_float4(o0, o1, o2, o3);
}

extern "C" void kernel_launch(void* const* d_in, const int* in_sizes, int n_in,
                              void* d_out, int out_size, void* d_ws, size_t ws_size,
                              hipStream_t stream)
{
    const float* rndata = (const float*)d_in[0];
    const float* qpos   = (const float*)d_in[1];
    const float* lpos   = (const float*)d_in[2];
    const int*   dst    = (const int*)d_in[3];
    const int*   src    = (const int*)d_in[4];
    const float* W0  = (const float*)d_in[5];
    const float* b0  = (const float*)d_in[6];
    const float* W1  = (const float*)d_in[7];
    const float* b1  = (const float*)d_in[8];
    const float* W2  = (const float*)d_in[9];
    const float* b2  = (const float*)d_in[10];
    const float* P0  = (const float*)d_in[11];
    const float* pb0 = (const float*)d_in[12];
    const float* P1  = (const float*)d_in[13];
    const float* pb1 = (const float*)d_in[14];

    int nq = in_sizes[1] / 3;
    int E  = in_sizes[3];

    // ws layout: [agg nq*128 (path A)] [hist] [cursor] [start] [dsts] [srcs]
    size_t agg_bytes  = (size_t)nq * 128 * sizeof(float);
    size_t sort_bytes = 0;
    {
        size_t o = 0;
        o += ((size_t)nq * sizeof(int) + 15) & ~(size_t)15;
        o += ((size_t)nq * sizeof(int) + 15) & ~(size_t)15;
        o += ((size_t)(nq + 1) * sizeof(int) + 15) & ~(size_t)15;
        o += ((size_t)E * sizeof(int) + 15) & ~(size_t)15;
        o += ((size_t)E * sizeof(int) + 15) & ~(size_t)15;
        sort_bytes = o;
    }
    bool path_a = (agg_bytes + sort_bytes) <= ws_size;

    size_t off = path_a ? agg_bytes : 0;
    auto alloc = [&](size_t bytes) {
        void* p = (char*)d_ws + off;
        off += (bytes + 15) & ~(size_t)15;
        return p;
    };
    float* agg   = (float*)d_ws;  // path A only
    int* hist    = (int*)alloc((size_t)nq * sizeof(int));
    int* cursor  = (int*)alloc((size_t)nq * sizeof(int));
    int* start   = (int*)alloc((size_t)(nq + 1) * sizeof(int));
    int* dsts    = (int*)alloc((size_t)E * sizeof(int));
    int* srcs    = (int*)alloc((size_t)E * sizeof(int));

    size_t histpad = ((size_t)nq * sizeof(int) + 15) & ~(size_t)15;
    hipMemsetAsync(hist, 0, 2 * histpad, stream);

    hist_kernel<<<(E + 255) / 256, 256, 0, stream>>>(dst, hist, E);
    scan_kernel<<<1, 1024, 0, stream>>>(hist, start, nq);
    scatter_kernel<<<(E + 255) / 256, 256, 0, stream>>>(dst, src, start, cursor, dsts, srcs, E);

    constexpr int    QB   = 24;
    constexpr size_t SMEM = (size_t)(5400 + QB * 129) * 4;  // 33,984 B -> 4 blocks/CU
    int nb = (nq + QB - 1) / QB;

    if (path_a) {
        fused_kernel<QB, false><<<nb, BLOCK, SMEM, stream>>>(
            rndata, qpos, lpos, dsts, srcs, start,
            W0, b0, W1, b1, W2, b2, P0, pb0, P1, pb1, agg, nullptr, nq);
        proj_kernel<<<(nq + 255) / 256, 256, 0, stream>>>(
            agg, P0, pb0, P1, pb1, (float*)d_out, nq);
    } else {
        fused_kernel<QB, true><<<nb, BLOCK, SMEM, stream>>>(
            rndata, qpos, lpos, dsts, srcs, start,
            W0, b0, W1, b1, W2, b2, P0, pb0, P1, pb1, nullptr, (float*)d_out, nq);
    }
}

// Round 19
// 1504.513 us; speedup vs baseline: 1.2342x; 1.0562x over previous
//
#include <hip/hip_runtime.h>

// GNODecoder round 19: r13-r18 converge at ~1250 us, VALUBusy 21-23% -- the
// invariant is B (weights) via VMEM with prefetch depth capped at the 60-VGPR
// grant. Fix: put B on the SCALAR pipe. One edge per lane (M=64/tile); each
// WAVE owns an n-slice (16 cols L0/L1, 32 cols L2) so B addresses are
// wave-uniform (readfirstlane) -> s_load; FMA = v_fmac vC, sB, vA (1 SGPR
// operand, legal). Per-wave B working set: W1-slice 4KB / W2-slice 8KB =
// sL1-resident after tile 0 (~30cyc, hidden). Accumulators 16/16/32 per
// phase (~50 VGPR live) and fission is HARMLESS (A re-read = 16 b128s,
// s_loads re-hit sL1). No LDS weight staging: LDS = hT[64][68] + sacc =
// 29.8 KB -> 5 blocks/CU. proj = plain r7/r9 (proven).

#define BLOCK 256

#define OFF_HT   0      // [64][68] m-major, 4352 floats
#define OFF_SACC 4352   // [QB*129]

__device__ __forceinline__ float gelu_f(float x) {
    // jax.nn.gelu default (approximate=True, tanh form)
    float x3 = x * x * x;
    float t  = 0.7978845608028654f * fmaf(0.044715f, x3, x);
    float e  = __expf(2.0f * t);
    float r  = __builtin_amdgcn_rcpf(e + 1.0f);
    return 0.5f * x * (1.0f + (1.0f - 2.0f * r));
}

// ---------- sort machinery (proven) ----------

__global__ void hist_kernel(const int* __restrict__ dst, int* __restrict__ hist, int E) {
    int e = blockIdx.x * blockDim.x + threadIdx.x;
    if (e < E) atomicAdd(&hist[dst[e]], 1);
}

__global__ __launch_bounds__(1024) void scan_kernel(const int* __restrict__ hist,
                                                    int* __restrict__ start, int n) {
    __shared__ int wsum[16];
    __shared__ int woff[16];
    int tid = threadIdx.x;
    int lane = tid & 63, wid = tid >> 6;
    int carry = 0;  // meaningful on tid 0 only
    for (int base = 0; base < n; base += 1024) {
        int i = base + tid;
        int v = (i < n) ? hist[i] : 0;
        int incl = v;
#pragma unroll
        for (int off = 1; off < 64; off <<= 1) {
            int t = __shfl_up(incl, off, 64);
            if (lane >= off) incl += t;
        }
        if (lane == 63) wsum[wid] = incl;
        __syncthreads();
        if (tid == 0) {
            int acc = carry;
#pragma unroll
            for (int w = 0; w < 16; ++w) { woff[w] = acc; acc += wsum[w]; }
            carry = acc;
        }
        __syncthreads();
        if (i < n) start[i] = woff[wid] + incl - v;
        __syncthreads();
    }
    if (threadIdx.x == 0) start[n] = carry;
}

__global__ void scatter_kernel(const int* __restrict__ dst, const int* __restrict__ src,
                               const int* __restrict__ start, int* __restrict__ cursor,
                               int* __restrict__ dsts, int* __restrict__ srcs, int E) {
    int e = blockIdx.x * blockDim.x + threadIdx.x;
    if (e >= E) return;
    int d = dst[e];
    int pos = start[d] + atomicAdd(&cursor[d], 1);
    dsts[pos] = d;
    srcs[pos] = src[e];
}

// ---------- fused: lane-per-edge, wave-per-n-slice, B via scalar pipe ----------

template <int QB, bool FUSED_PROJ>
__global__ __launch_bounds__(BLOCK) void fused_kernel(
    const float* __restrict__ rndata,   // [NL,128]
    const float* __restrict__ qpos,     // [NQ,3]
    const float* __restrict__ lpos,     // [NL,3]
    const int*   __restrict__ dsts,     // [E] sorted by dst
    const int*   __restrict__ srcs,     // [E]
    const int*   __restrict__ start,    // [NQ+1]
    const float* __restrict__ W0, const float* __restrict__ b0,
    const float* __restrict__ W1, const float* __restrict__ b1,
    const float* __restrict__ W2, const float* __restrict__ b2,
    const float* __restrict__ P0, const float* __restrict__ pb0,
    const float* __restrict__ P1, const float* __restrict__ pb1,
    float* __restrict__ agg,            // [NQ,128] mean (path A)
    float* __restrict__ out,            // [NQ,4]   (FUSED_PROJ)
    int nq)
{
    extern __shared__ float smem[];
    const int tid = threadIdx.x;
    float* hT   = smem + OFF_HT;    // [64][68] row m = edge-lane, cols = h channels
    float* sacc = smem + OFF_SACC;  // [QB][129]

    for (int i = tid; i < QB * 129; i += BLOCK) sacc[i] = 0.f;

    const int q0   = blockIdx.x * QB;
    const int qend = min(q0 + QB, nq);
    const int e0 = start[q0], e1 = start[qend];
    const int ntiles = (e1 - e0 + 63) >> 6;

    const int m  = tid & 63;                                    // edge row
    const int wn1 = __builtin_amdgcn_readfirstlane((tid >> 6) * 16);  // L0/L1 n-slice
    const int wn2 = __builtin_amdgcn_readfirstlane((tid >> 6) * 32);  // L2 n-slice

    for (int t = 0; t < ntiles; ++t) {
        const int ebase = e0 + (t << 6);
        int  e     = ebase + m;
        bool valid = e < e1;
        int  d = valid ? dsts[e] : q0;
        int  s = valid ? srcs[e] : 0;
        float pin[6];
        {
            const float* pq = qpos + d * 3;
            pin[0] = pq[0]; pin[1] = pq[1]; pin[2] = pq[2];
            const float* pl = lpos + s * 3;
            pin[3] = pl[0]; pin[4] = pl[1]; pin[5] = pl[2];
        }

        // ---- L0: h0[m][wn1..wn1+16) ; B = W0 via s_load ----
        float C0[16];
#pragma unroll
        for (int j = 0; j < 16; ++j) C0[j] = b0[wn1 + j];
#pragma unroll
        for (int k = 0; k < 6; ++k) {
            float a = pin[k];
#pragma unroll
            for (int j = 0; j < 16; ++j)
                C0[j] = fmaf(a, W0[k * 64 + wn1 + j], C0[j]);
        }
        __syncthreads();  // prev tile's L2 reads done (t==0: sacc init visible)
#pragma unroll
        for (int j4 = 0; j4 < 4; ++j4) {
            float4 o = make_float4(gelu_f(C0[4 * j4 + 0]), gelu_f(C0[4 * j4 + 1]),
                                   gelu_f(C0[4 * j4 + 2]), gelu_f(C0[4 * j4 + 3]));
            *(float4*)(hT + m * 68 + wn1 + 4 * j4) = o;
        }
        __syncthreads();  // h0 ready

        // ---- L1: C1[16] over k=0..63 ; A = hT[m][k] (own row), B = W1 s_load ----
        float C1[16];
#pragma unroll
        for (int j = 0; j < 16; ++j) C1[j] = b1[wn1 + j];
#pragma unroll 2
        for (int k4 = 0; k4 < 16; ++k4) {
            float4 a4 = *(const float4*)(hT + m * 68 + k4 * 4);
            float av[4] = {a4.x, a4.y, a4.z, a4.w};
#pragma unroll
            for (int kk = 0; kk < 4; ++kk) {
                float a = av[kk];
#pragma unroll
                for (int j = 0; j < 16; ++j)
                    C1[j] = fmaf(a, W1[(k4 * 4 + kk) * 64 + wn1 + j], C1[j]);
            }
        }
        __syncthreads();  // all h0 reads done
#pragma unroll
        for (int j4 = 0; j4 < 4; ++j4) {
            float4 o = make_float4(gelu_f(C1[4 * j4 + 0]), gelu_f(C1[4 * j4 + 1]),
                                   gelu_f(C1[4 * j4 + 2]), gelu_f(C1[4 * j4 + 3]));
            *(float4*)(hT + m * 68 + wn1 + 4 * j4) = o;
        }
        __syncthreads();  // h1 ready

        // ---- L2: C2[32] over k=0..63 ; B = W2 s_load ; epilogue ds_add ----
        float C2[32];
#pragma unroll
        for (int j = 0; j < 32; ++j) C2[j] = b2[wn2 + j];
#pragma unroll 2
        for (int k4 = 0; k4 < 16; ++k4) {
            float4 a4 = *(const float4*)(hT + m * 68 + k4 * 4);
            float av[4] = {a4.x, a4.y, a4.z, a4.w};
#pragma unroll
            for (int kk = 0; kk < 4; ++kk) {
                float a = av[kk];
#pragma unroll
                for (int j = 0; j < 32; ++j)
                    C2[j] = fmaf(a, W2[(k4 * 4 + kk) * 128 + wn2 + j], C2[j]);
            }
        }
        if (valid) {
            const float* r  = rndata + (size_t)s * 128 + wn2;
            float*       ac = &sacc[(d - q0) * 129 + wn2];
#pragma unroll
            for (int j4 = 0; j4 < 8; ++j4) {
                float4 rv = *(const float4*)(r + 4 * j4);
                atomicAdd(&ac[4 * j4 + 0], C2[4 * j4 + 0] * rv.x);
                atomicAdd(&ac[4 * j4 + 1], C2[4 * j4 + 1] * rv.y);
                atomicAdd(&ac[4 * j4 + 2], C2[4 * j4 + 2] * rv.z);
                atomicAdd(&ac[4 * j4 + 3], C2[4 * j4 + 3] * rv.w);
            }
        }
        // next iteration's first barrier orders these L2 reads/ds_adds
    }
    __syncthreads();  // last tile's ds_adds visible (and ntiles==0 init path)

    if (!FUSED_PROJ) {
        // write per-query mean to global agg (coalesced across c)
        for (int idx = tid; idx < QB * 128; idx += BLOCK) {
            int ql = idx >> 7, c = idx & 127;
            int q  = q0 + ql;
            if (q < qend) {
                float deg = (float)(start[q + 1] - start[q]);
                agg[(size_t)q * 128 + c] = sacc[ql * 129 + c] / fmaxf(deg, 1.f);
            }
        }
    } else {
        if (tid < QB) {
            int q = q0 + tid;
            if (q < nq) {
                float deg = (float)(start[q + 1] - start[q]);
                float inv = 1.0f / fmaxf(deg, 1.f);
                const float* aq = &sacc[tid * 129];
                float o0 = pb1[0], o1 = pb1[1], o2 = pb1[2], o3 = pb1[3];
#pragma unroll 1
                for (int jj = 0; jj < 256; jj += 8) {
                    float acc[8];
#pragma unroll
                    for (int u = 0; u < 8; ++u) acc[u] = pb0[jj + u];
#pragma unroll
                    for (int i = 0; i < 128; ++i) {
                        float av = aq[i] * inv;
#pragma unroll
                        for (int u = 0; u < 8; ++u)
                            acc[u] = fmaf(av, P0[i * 256 + jj + u], acc[u]);
                    }
#pragma unroll
                    for (int u = 0; u < 8; ++u) {
                        float h = gelu_f(acc[u]);
                        o0 = fmaf(h, P1[(jj + u) * 4 + 0], o0);
                        o1 = fmaf(h, P1[(jj + u) * 4 + 1], o1);
                        o2 = fmaf(h, P1[(jj + u) * 4 + 2], o2);
                        o3 = fmaf(h, P1[(jj + u) * 4 + 3], o3);
                    }
                }
                float4* o4 = (float4*)(out + (size_t)q * 4);
                *o4 = make_float4(o0, o1, o2, o3);
            }
        }
    }
}

// ---------- projection: plain r7/r9 kernel (proven ~270 us) ----------

__global__ __launch_bounds__(256) void proj_kernel(
    const float* __restrict__ agg,      // [NQ,128] mean
    const float* __restrict__ P0, const float* __restrict__ pb0,
    const float* __restrict__ P1, const float* __restrict__ pb1,
    float* __restrict__ out, int nq)
{
    int q = blockIdx.x * blockDim.x + threadIdx.x;
    if (q >= nq) return;

    float a[128];
    const float4* ag4 = (const float4*)(agg + (size_t)q * 128);
#pragma unroll
    for (int i = 0; i < 32; ++i) {
        float4 v = ag4[i];
        a[4 * i + 0] = v.x; a[4 * i + 1] = v.y;
        a[4 * i + 2] = v.z; a[4 * i + 3] = v.w;
    }

    float o0 = pb1[0], o1 = pb1[1], o2 = pb1[2], o3 = pb1[3];
#pragma unroll 1
    for (int jj = 0; jj < 256; jj += 8) {
        float acc[8];
#pragma unroll
        for (int u = 0; u < 8; ++u) acc[u] = pb0[jj + u];
#pragma unroll
        for (int i = 0; i < 128; ++i) {
            float av = a[i];
#pragma unroll
            for (int u = 0; u < 8; ++u)
                acc[u] = fmaf(av, P0[i * 256 + jj + u], acc[u]);
        }
#pragma unroll
        for (int u = 0; u < 8; ++u) {
            float h = gelu_f(acc[u]);
            o0 = fmaf(h, P1[(jj + u) * 4 + 0], o0);
            o1 = fmaf(h, P1[(jj + u) * 4 + 1], o1);
            o2 = fmaf(h, P1[(jj + u) * 4 + 2], o2);
            o3 = fmaf(h, P1[(jj + u) * 4 + 3], o3);
        }
    }
    float4* o4 = (float4*)(out + (size_t)q * 4);
    *o4 = make_float4(o0, o1, o2, o3);
}

extern "C" void kernel_launch(void* const* d_in, const int* in_sizes, int n_in,
                              void* d_out, int out_size, void* d_ws, size_t ws_size,
                              hipStream_t stream)
{
    const float* rndata = (const float*)d_in[0];
    const float* qpos   = (const float*)d_in[1];
    const float* lpos   = (const float*)d_in[2];
    const int*   dst    = (const int*)d_in[3];
    const int*   src    = (const int*)d_in[4];
    const float* W0  = (const float*)d_in[5];
    const float* b0  = (const float*)d_in[6];
    const float* W1  = (const float*)d_in[7];
    const float* b1  = (const float*)d_in[8];
    const float* W2  = (const float*)d_in[9];
    const float* b2  = (const float*)d_in[10];
    const float* P0  = (const float*)d_in[11];
    const float* pb0 = (const float*)d_in[12];
    const float* P1  = (const float*)d_in[13];
    const float* pb1 = (const float*)d_in[14];

    int nq = in_sizes[1] / 3;
    int E  = in_sizes[3];

    // ws layout: [agg nq*128 (path A)] [hist] [cursor] [start] [dsts] [srcs]
    size_t agg_bytes  = (size_t)nq * 128 * sizeof(float);
    size_t sort_bytes = 0;
    {
        size_t o = 0;
        o += ((size_t)nq * sizeof(int) + 15) & ~(size_t)15;
        o += ((size_t)nq * sizeof(int) + 15) & ~(size_t)15;
        o += ((size_t)(nq + 1) * sizeof(int) + 15) & ~(size_t)15;
        o += ((size_t)E * sizeof(int) + 15) & ~(size_t)15;
        o += ((size_t)E * sizeof(int) + 15) & ~(size_t)15;
        sort_bytes = o;
    }
    bool path_a = (agg_bytes + sort_bytes) <= ws_size;

    size_t off = path_a ? agg_bytes : 0;
    auto alloc = [&](size_t bytes) {
        void* p = (char*)d_ws + off;
        off += (bytes + 15) & ~(size_t)15;
        return p;
    };
    float* agg   = (float*)d_ws;  // path A only
    int* hist    = (int*)alloc((size_t)nq * sizeof(int));
    int* cursor  = (int*)alloc((size_t)nq * sizeof(int));
    int* start   = (int*)alloc((size_t)(nq + 1) * sizeof(int));
    int* dsts    = (int*)alloc((size_t)E * sizeof(int));
    int* srcs    = (int*)alloc((size_t)E * sizeof(int));

    size_t histpad = ((size_t)nq * sizeof(int) + 15) & ~(size_t)15;
    hipMemsetAsync(hist, 0, 2 * histpad, stream);

    hist_kernel<<<(E + 255) / 256, 256, 0, stream>>>(dst, hist, E);
    scan_kernel<<<1, 1024, 0, stream>>>(hist, start, nq);
    scatter_kernel<<<(E + 255) / 256, 256, 0, stream>>>(dst, src, start, cursor, dsts, srcs, E);

    constexpr int    QB   = 24;
    constexpr size_t SMEM = (size_t)(4352 + QB * 129) * 4;  // 29,792 B -> 5 blocks/CU
    int nb = (nq + QB - 1) / QB;

    if (path_a) {
        fused_kernel<QB, false><<<nb, BLOCK, SMEM, stream>>>(
            rndata, qpos, lpos, dsts, srcs, start,
            W0, b0, W1, b1, W2, b2, P0, pb0, P1, pb1, agg, nullptr, nq);
        proj_kernel<<<(nq + 255) / 256, 256, 0, stream>>>(
            agg, P0, pb0, P1, pb1, (float*)d_out, nq);
    } else {
        fused_kernel<QB, true><<<nb, BLOCK, SMEM, stream>>>(
            rndata, qpos, lpos, dsts, srcs, start,
            W0, b0, W1, b1, W2, b2, P0, pb0, P1, pb1, nullptr, (float*)d_out, nq);
    }
}